// Round 5
// baseline (300.412 us; speedup 1.0000x reference)
//
#include <hip/hip_runtime.h>
#include <hip/hip_bf16.h>

#ifndef M_PI
#define M_PI 3.14159265358979323846
#endif

static constexpr int B_ = 128;   // batch
static constexpr int N_ = 3136;  // tokens
static constexpr int C_ = 96;    // channels
static constexpr int NC = N_ * C_;
static constexpr int PITCH = 104;  // fallback kernel LDS pitch

typedef short short8 __attribute__((ext_vector_type(8)));
typedef float float4v __attribute__((ext_vector_type(4)));

static __device__ __forceinline__ unsigned short f2bf(float f) {
  __hip_bfloat16 b = __float2bfloat16(f);
  return *reinterpret_cast<unsigned short*>(&b);
}

// XCD-contiguous token map: HW dispatches block bid to XCD bid%8; give each
// XCD a contiguous 392-token slab. 3136 = 8*392 exactly -> bijective.
static __device__ __forceinline__ int token_of_block(int bid) {
  return (bid & 7) * 392 + (bid >> 3);
}

// ---------------------------------------------------------------------------
// Kernel 1: per token n, h_n = irfft(w_n, 96) (backward norm; Im of DC/Nyquist
// ignored = pocketfft c2r). Write 8 shifted bf16 replicas:
//   wsB[n][s][j] = bf16(ext_n[j + s]),  s in 0..7, j in 0..191
//   ext_n[u] = h_n[(288 - u) % 96]
// ---------------------------------------------------------------------------
__global__ __launch_bounds__(128) void gf_hbuild_kernel(
    const float* __restrict__ wc, unsigned short* __restrict__ wsB) {
  const int n = token_of_block(blockIdx.x);
  const int tid = threadIdx.x;
  __shared__ float wsh[98];
  __shared__ float cs[96], sn[96];
  __shared__ unsigned short hlb[96];

  if (tid < 98) wsh[tid] = wc[n * 98 + tid];
  if (tid < 96) {
    float s, c;
    sincosf((float)(2.0 * M_PI / 96.0) * (float)tid, &s, &c);
    cs[tid] = c;
    sn[tid] = s;
  }
  __syncthreads();

  if (tid < 96) {
    const int c = tid;
    float acc = wsh[0] + ((c & 1) ? -wsh[96] : wsh[96]);  // DC + Nyquist (re)
    int idx = c;
    for (int k = 1; k <= 47; ++k) {
      acc += 2.0f * (wsh[2 * k] * cs[idx] - wsh[2 * k + 1] * sn[idx]);
      idx += c;
      if (idx >= 96) idx -= 96;
    }
    hlb[c] = f2bf(acc * (1.0f / 96.0f));
  }
  __syncthreads();

  unsigned int* out = reinterpret_cast<unsigned int*>(wsB + (size_t)n * 1536);
  for (int e = tid; e < 768; e += 128) {
    const int s = e / 96;
    const int jp = e - s * 96;
    const int a = 288 - (2 * jp + s);
    const unsigned int lo = hlb[a % 96];
    const unsigned int hi = hlb[(a - 1) % 96];
    out[e] = lo | (hi << 16);
  }
}

// ---------------------------------------------------------------------------
// Kernel 2: streaming MFMA, no LDS/barriers, SWAPPED operands:
//   A = H_n rows (M = channel c), B = x rows (N = batch b)
//   D[c][b]: row=(lane>>4)*4+reg = c -> each lane holds 4 consecutive
//   channels at fixed b => fully coalesced dwordx4 stores.
// ---------------------------------------------------------------------------
__global__ __launch_bounds__(256, 4) void gf_mfma3_kernel(
    const float* __restrict__ x, const unsigned short* __restrict__ wsB,
    float* __restrict__ y) {
  const int n = token_of_block(blockIdx.x);
  const int tid = threadIdx.x;
  const int wv = tid >> 6;   // wave 0..3, owns b-tiles {2wv, 2wv+1}
  const int l = tid & 63;
  const int lrow = l & 15;   // A-row(c) / B-col(b) / D-col(b) within tile
  const int lk = l >> 4;     // k-group

  // ---- B fragments: x rows (fp32 -> bf16) ----
  float4 v0[2][3], v1[2][3];
#pragma unroll
  for (int bt = 0; bt < 2; ++bt) {
    const float* xp =
        x + (size_t)((wv * 2 + bt) * 16 + lrow) * NC + n * C_ + lk * 8;
#pragma unroll
    for (int kq = 0; kq < 3; ++kq) {
      v0[bt][kq] = *reinterpret_cast<const float4*>(xp + kq * 32);
      v1[bt][kq] = *reinterpret_cast<const float4*>(xp + kq * 32 + 4);
    }
  }
  short8 xfr[2][3];
#pragma unroll
  for (int bt = 0; bt < 2; ++bt)
#pragma unroll
    for (int kq = 0; kq < 3; ++kq) {
      short8 a;
      a[0] = (short)f2bf(v0[bt][kq].x);
      a[1] = (short)f2bf(v0[bt][kq].y);
      a[2] = (short)f2bf(v0[bt][kq].z);
      a[3] = (short)f2bf(v0[bt][kq].w);
      a[4] = (short)f2bf(v1[bt][kq].x);
      a[5] = (short)f2bf(v1[bt][kq].y);
      a[6] = (short)f2bf(v1[bt][kq].z);
      a[7] = (short)f2bf(v1[bt][kq].w);
      xfr[bt][kq] = a;
    }

  // ---- A fragment base (filter replicas): same addressing as round 3 ----
  // m = 96 + (kq*32 + lk*8) - (nt*16 + lrow); s = m&7 is (kq,nt)-invariant
  const int M0 = 96 + lk * 8 - lrow;
  const unsigned short* wb0 =
      wsB + (size_t)n * 1536 + (M0 & 7) * 192 + (M0 & ~7);

  float4v acc[2][6];
#pragma unroll
  for (int bt = 0; bt < 2; ++bt)
#pragma unroll
    for (int nt = 0; nt < 6; ++nt)
#pragma unroll
      for (int i = 0; i < 4; ++i) acc[bt][nt][i] = 0.0f;

#pragma unroll
  for (int nt = 0; nt < 6; ++nt) {
#pragma unroll
    for (int kq = 0; kq < 3; ++kq) {
      const short8 hfr =
          *reinterpret_cast<const short8*>(wb0 + kq * 32 - nt * 16);
      acc[0][nt] = __builtin_amdgcn_mfma_f32_16x16x32_bf16(hfr, xfr[0][kq],
                                                           acc[0][nt], 0, 0, 0);
      acc[1][nt] = __builtin_amdgcn_mfma_f32_16x16x32_bf16(hfr, xfr[1][kq],
                                                           acc[1][nt], 0, 0, 0);
    }
  }

  // ---- epilogue: D col=lane&15 -> b, row=lk*4+reg -> c. float4 stores ----
#pragma unroll
  for (int bt = 0; bt < 2; ++bt) {
    float* yp = y + (size_t)((wv * 2 + bt) * 16 + lrow) * NC +
                (size_t)n * C_ + lk * 4;
#pragma unroll
    for (int nt = 0; nt < 6; ++nt) {
      __builtin_nontemporal_store(
          acc[bt][nt], reinterpret_cast<float4v*>(yp + nt * 16));
    }
  }
}

// ---------------------------------------------------------------------------
// Fallback (round-2 fused kernel) if ws_size is too small for the h tables.
// ---------------------------------------------------------------------------
__global__ __launch_bounds__(256, 3) void gf_mfma_kernel(
    const float* __restrict__ x, const float* __restrict__ wc,
    float* __restrict__ y) {
  const int n = blockIdx.x;
  const int tid = threadIdx.x;

  __shared__ __align__(16) unsigned short Asm[128 * PITCH];
  __shared__ __align__(16) unsigned short Ht[96 * PITCH];
  __shared__ float wsh[98];
  __shared__ float cs[96];
  __shared__ float sn[96];
  __shared__ unsigned short hrevd[192];

  float4 xv[12];
  const float* xbase = x + (size_t)n * C_;
#pragma unroll
  for (int p = 0; p < 12; ++p) {
    const int fidx = p * 256 + tid;
    const int b = fidx / 24;
    const int t4 = fidx - b * 24;
    xv[p] = *reinterpret_cast<const float4*>(xbase + (size_t)b * NC + 4 * t4);
  }

  if (tid < 98) wsh[tid] = wc[n * 98 + tid];
  if (tid < 96) {
    float s, c;
    sincosf((float)(2.0 * M_PI / 96.0) * (float)tid, &s, &c);
    cs[tid] = c;
    sn[tid] = s;
  }
  __syncthreads();

  if (tid < 96) {
    const int c = tid;
    float acc = wsh[0] + ((c & 1) ? -wsh[96] : wsh[96]);
    int idx = c;
    for (int k = 1; k <= 47; ++k) {
      acc += 2.0f * (wsh[2 * k] * cs[idx] - wsh[2 * k + 1] * sn[idx]);
      idx += c;
      if (idx >= 96) idx -= 96;
    }
    const unsigned short hb = f2bf(acc * (1.0f / 96.0f));
    hrevd[96 - c] = hb;
    hrevd[(c == 0) ? 0 : (192 - c)] = hb;
  }

#pragma unroll
  for (int p = 0; p < 12; ++p) {
    const int fidx = p * 256 + tid;
    const int b = fidx / 24;
    const int t4 = fidx - b * 24;
    ushort4 o;
    o.x = f2bf(xv[p].x);
    o.y = f2bf(xv[p].y);
    o.z = f2bf(xv[p].z);
    o.w = f2bf(xv[p].w);
    *reinterpret_cast<ushort4*>(&Asm[b * PITCH + 4 * t4]) = o;
  }
  __syncthreads();

  for (int j = tid; j < 96 * 48; j += 256) {
    const int c = j / 48;
    const int kp = j - c * 48;
    const int m = 96 - c + 2 * kp;
    const unsigned int lo = hrevd[m];
    const unsigned int hi = hrevd[m + 1];
    *reinterpret_cast<unsigned int*>(&Ht[c * PITCH + 2 * kp]) = lo | (hi << 16);
  }
  __syncthreads();

  const int wv = tid >> 6;
  const int l = tid & 63;
  const int lrow = l & 15;
  const int lk = l >> 4;

  float4v acc[2][6];
#pragma unroll
  for (int mt = 0; mt < 2; ++mt)
#pragma unroll
    for (int nt = 0; nt < 6; ++nt)
#pragma unroll
      for (int i = 0; i < 4; ++i) acc[mt][nt][i] = 0.0f;

  short8 afr[2][3];
#pragma unroll
  for (int mt = 0; mt < 2; ++mt)
#pragma unroll
    for (int kq = 0; kq < 3; ++kq)
      afr[mt][kq] = *reinterpret_cast<const short8*>(
          &Asm[((wv * 2 + mt) * 16 + lrow) * PITCH + kq * 32 + lk * 8]);

#pragma unroll
  for (int nt = 0; nt < 6; ++nt) {
#pragma unroll
    for (int kq = 0; kq < 3; ++kq) {
      const short8 bfr = *reinterpret_cast<const short8*>(
          &Ht[(nt * 16 + lrow) * PITCH + kq * 32 + lk * 8]);
      acc[0][nt] = __builtin_amdgcn_mfma_f32_16x16x32_bf16(afr[0][kq], bfr,
                                                           acc[0][nt], 0, 0, 0);
      acc[1][nt] = __builtin_amdgcn_mfma_f32_16x16x32_bf16(afr[1][kq], bfr,
                                                           acc[1][nt], 0, 0, 0);
    }
  }

#pragma unroll
  for (int mt = 0; mt < 2; ++mt) {
    const int brow0 = (wv * 2 + mt) * 16 + lk * 4;
#pragma unroll
    for (int i = 0; i < 4; ++i) {
      float* yp = y + (size_t)(brow0 + i) * NC + (size_t)n * C_;
#pragma unroll
      for (int nt = 0; nt < 6; ++nt) {
        yp[nt * 16 + lrow] = acc[mt][nt][i];
      }
    }
  }
}

extern "C" void kernel_launch(void* const* d_in, const int* in_sizes, int n_in,
                              void* d_out, int out_size, void* d_ws, size_t ws_size,
                              hipStream_t stream) {
  const float* x = (const float*)d_in[0];   // [B, N, C] fp32
  const float* wc = (const float*)d_in[1];  // [N, 49, 2] fp32
  float* y = (float*)d_out;                 // [B, N, C] fp32

  const size_t need = (size_t)N_ * 1536 * sizeof(unsigned short);  // 9.63 MB
  if (ws_size >= need) {
    unsigned short* wsB = (unsigned short*)d_ws;
    hipLaunchKernelGGL(gf_hbuild_kernel, dim3(N_), dim3(128), 0, stream, wc, wsB);
    hipLaunchKernelGGL(gf_mfma3_kernel, dim3(N_), dim3(256), 0, stream, x, wsB, y);
  } else {
    hipLaunchKernelGGL(gf_mfma_kernel, dim3(N_), dim3(256), 0, stream, x, wc, y);
  }
}

// Round 6
// 285.974 us; speedup vs baseline: 1.0505x; 1.0505x over previous
//
#include <hip/hip_runtime.h>
#include <hip/hip_bf16.h>

#ifndef M_PI
#define M_PI 3.14159265358979323846
#endif

static constexpr int B_ = 128;   // batch
static constexpr int N_ = 3136;  // tokens
static constexpr int C_ = 96;    // channels
static constexpr int NC = N_ * C_;

typedef short short8 __attribute__((ext_vector_type(8)));
typedef float float4v __attribute__((ext_vector_type(4)));

static __device__ __forceinline__ unsigned short f2bf(float f) {
  __hip_bfloat16 b = __float2bfloat16(f);
  return *reinterpret_cast<unsigned short*>(&b);
}

static __device__ __forceinline__ int mod96(int a) {
  // a in [0, 288)
  return a >= 192 ? a - 192 : (a >= 96 ? a - 96 : a);
}

// ---------------------------------------------------------------------------
// Single fused kernel, one block per token n.
//   y[:,n,:] = x[:,n,:] (128x96) @ H_n (96x96 circulant), bf16 MFMA,
//   H_n[c][k] = h_n[(c-k) mod 96], h_n = irfft(w_n, 96) backward-norm
//   (Im of DC/Nyquist ignored = pocketfft c2r semantics).
// Swapped operands: A = filter rows (M=c), B = x rows (N=b) so the D layout
// (row = lk*4+reg = c) makes the epilogue fully-coalesced dwordx4 stores.
// Filter A-fragments come from an 8-shift replica table in LDS (3 KB) so
// every ds_read_b128 is 16B-aligned:
//   hrep[s][j] = bf16(ext[j+s]), ext[u] = h[(288-u) % 96], s<8, j<192.
// ---------------------------------------------------------------------------
__global__ __launch_bounds__(256, 4) void gf_fused_kernel(
    const float* __restrict__ x, const float* __restrict__ wc,
    float* __restrict__ y) {
  const int n = blockIdx.x;
  const int tid = threadIdx.x;
  const int wv = tid >> 6;   // wave 0..3, owns b-tiles {2wv, 2wv+1}
  const int l = tid & 63;
  const int lrow = l & 15;   // A-row(c) / B-col(b) within tile
  const int lk = l >> 4;     // k-group

  __shared__ float wsh[98];
  __shared__ float cs[96], sn[96];
  __shared__ float hpart[2][96];
  __shared__ __align__(16) unsigned short hrep[1536];  // 8 shifts x 192

  // ---- issue x loads first (12 independent dwordx4, held in regs) ----
  float4 v0[2][3], v1[2][3];
#pragma unroll
  for (int bt = 0; bt < 2; ++bt) {
    const float* xp =
        x + (size_t)((wv * 2 + bt) * 16 + lrow) * NC + n * C_ + lk * 8;
#pragma unroll
    for (int kq = 0; kq < 3; ++kq) {
      v0[bt][kq] = *reinterpret_cast<const float4*>(xp + kq * 32);
      v1[bt][kq] = *reinterpret_cast<const float4*>(xp + kq * 32 + 4);
    }
  }

  // ---- weights + twiddle tables ----
  if (tid < 98) wsh[tid] = wc[n * 98 + tid];
  if (tid < 96) {
    float s, c;
    sincosf((float)(2.0 * M_PI / 96.0) * (float)tid, &s, &c);
    cs[tid] = c;
    sn[tid] = s;
  }
  __syncthreads();

  // ---- h-build split over 192 lanes: c x {k=1..24 | k=25..47} ----
  if (tid < 192) {
    const int half = (tid >= 96) ? 1 : 0;
    const int c = tid - half * 96;
    float acc;
    int idx, k0, k1;
    if (half == 0) {
      acc = wsh[0] + ((c & 1) ? -wsh[96] : wsh[96]);  // DC + Nyquist (re)
      idx = c;
      k0 = 1; k1 = 24;
    } else {
      acc = 0.0f;
      int m0 = 24 * (c & 3) + c;      // (25*c) % 96 seed
      if (m0 >= 96) m0 -= 96;
      idx = m0;
      k0 = 25; k1 = 47;
    }
    for (int k = k0; k <= k1; ++k) {
      acc += 2.0f * (wsh[2 * k] * cs[idx] - wsh[2 * k + 1] * sn[idx]);
      idx += c;
      if (idx >= 96) idx -= 96;
    }
    hpart[half][c] = acc;
  }
  __syncthreads();

  // ---- build 8-shift replica table (768 u32 writes, 3 per thread) ----
  {
    unsigned int* out = reinterpret_cast<unsigned int*>(hrep);
#pragma unroll
    for (int r = 0; r < 3; ++r) {
      const int e = r * 256 + tid;           // 0..767
      const int s = e / 96;
      const int jp = e - s * 96;
      const int a = 288 - (2 * jp + s);      // in [91, 288)
      const int i0 = mod96(a);
      const int i1 = mod96(a - 1);
      const unsigned int lo =
          f2bf((hpart[0][i0] + hpart[1][i0]) * (1.0f / 96.0f));
      const unsigned int hi =
          f2bf((hpart[0][i1] + hpart[1][i1]) * (1.0f / 96.0f));
      out[e] = lo | (hi << 16);
    }
  }

  // ---- convert x to bf16 B-fragments (waits on the global loads) ----
  short8 xfr[2][3];
#pragma unroll
  for (int bt = 0; bt < 2; ++bt)
#pragma unroll
    for (int kq = 0; kq < 3; ++kq) {
      short8 a;
      a[0] = (short)f2bf(v0[bt][kq].x);
      a[1] = (short)f2bf(v0[bt][kq].y);
      a[2] = (short)f2bf(v0[bt][kq].z);
      a[3] = (short)f2bf(v0[bt][kq].w);
      a[4] = (short)f2bf(v1[bt][kq].x);
      a[5] = (short)f2bf(v1[bt][kq].y);
      a[6] = (short)f2bf(v1[bt][kq].z);
      a[7] = (short)f2bf(v1[bt][kq].w);
      xfr[bt][kq] = a;
    }
  __syncthreads();

  // ---- MFMA main loop; A-frags via aligned ds_read_b128 from hrep ----
  // m = 96 + lk*8 - lrow + kq*32 - nt*16; shift s = m&7 is (kq,nt)-invariant
  const int M0 = 96 + lk * 8 - lrow;
  const unsigned short* wb0 = hrep + (M0 & 7) * 192 + (M0 & ~7);

  float4v acc[2][6];
#pragma unroll
  for (int bt = 0; bt < 2; ++bt)
#pragma unroll
    for (int nt = 0; nt < 6; ++nt)
#pragma unroll
      for (int i = 0; i < 4; ++i) acc[bt][nt][i] = 0.0f;

#pragma unroll
  for (int nt = 0; nt < 6; ++nt) {
#pragma unroll
    for (int kq = 0; kq < 3; ++kq) {
      const short8 hfr =
          *reinterpret_cast<const short8*>(wb0 + kq * 32 - nt * 16);
      acc[0][nt] = __builtin_amdgcn_mfma_f32_16x16x32_bf16(hfr, xfr[0][kq],
                                                           acc[0][nt], 0, 0, 0);
      acc[1][nt] = __builtin_amdgcn_mfma_f32_16x16x32_bf16(hfr, xfr[1][kq],
                                                           acc[1][nt], 0, 0, 0);
    }
  }

  // ---- epilogue: D col=lrow -> b, row=lk*4+reg -> c. Plain dwordx4 ----
#pragma unroll
  for (int bt = 0; bt < 2; ++bt) {
    float* yp = y + (size_t)((wv * 2 + bt) * 16 + lrow) * NC +
                (size_t)n * C_ + lk * 4;
#pragma unroll
    for (int nt = 0; nt < 6; ++nt) {
      *reinterpret_cast<float4v*>(yp + nt * 16) = acc[bt][nt];
    }
  }
}

extern "C" void kernel_launch(void* const* d_in, const int* in_sizes, int n_in,
                              void* d_out, int out_size, void* d_ws, size_t ws_size,
                              hipStream_t stream) {
  const float* x = (const float*)d_in[0];   // [B, N, C] fp32
  const float* wc = (const float*)d_in[1];  // [N, 49, 2] fp32
  float* y = (float*)d_out;                 // [B, N, C] fp32

  hipLaunchKernelGGL(gf_fused_kernel, dim3(N_), dim3(256), 0, stream, x, wc, y);
}